// Round 5
// baseline (154.312 us; speedup 1.0000x reference)
//
#include <hip/hip_runtime.h>
#include <hip/hip_bf16.h>
#include <math.h>

// Polynomial feature map: Xp = X @ P; out = [bias | Xp | Xp^2 | Xp^3 | pairs | sqrt(|Xp|+eps)]
// X: [16384, 2048] f32, P: [2048, 512] f32, out: [16384, 2561] f32.
// pairs (triu k=1, first 512): c<511 -> Xp[:,0]*Xp[:,c+1]; c==511 -> Xp[:,1]*Xp[:,2]
//
// Path: prep_b (P -> Bt bf16 [512][2048] in ws) ; gemm5 (128x128 tile, 3-deep pipelined
// LDS, ALL staging via global_load_lds, counted vmcnt(6) -- never 0 in main loop,
// raw s_barrier, A kept f32 in LDS with cvt at fragment read) writes p1 ;
// epi_k expands remaining regions reading p1 back (L2/L3-hot).

typedef __attribute__((ext_vector_type(4))) float f32x4;
typedef __attribute__((ext_vector_type(8))) short bf16x8;

#define MM 16384
#define NN 512
#define KK 2048
#define OUTW 2561

#define BM 128
#define BN 128
#define BK 32
#define NT (KK / BK)  // 64

__device__ __forceinline__ short f2bf(float x) {
  union { __hip_bfloat16 b; short s; } u;
  u.b = __float2bfloat16(x);  // hw RNE; compiler pairs into v_cvt_pk_bf16_f32
  return u.s;
}

__device__ __forceinline__ bf16x8 cvt8(f32x4 a, f32x4 b) {
  bf16x8 r;
  r[0] = f2bf(a[0]); r[1] = f2bf(a[1]); r[2] = f2bf(a[2]); r[3] = f2bf(a[3]);
  r[4] = f2bf(b[0]); r[5] = f2bf(b[1]); r[6] = f2bf(b[2]); r[7] = f2bf(b[3]);
  return r;
}

__device__ __forceinline__ void gl_lds16(const void* g, void* l) {
  __builtin_amdgcn_global_load_lds((const __attribute__((address_space(1))) unsigned int*)g,
                                   (__attribute__((address_space(3))) unsigned int*)l, 16, 0, 0);
}

// ---------------- prep: P [K][N] f32 -> Bt [N][K] bf16 ----------------
__global__ __launch_bounds__(256) void prep_b(const float* __restrict__ P, short* __restrict__ Bt) {
  __shared__ float ts[64][65];
  const int tid = threadIdx.x;
  const int k0 = (blockIdx.x >> 3) * 64;  // 32 k-blocks
  const int n0 = (blockIdx.x & 7) * 64;   // 8 n-blocks
#pragma unroll
  for (int j = 0; j < 16; ++j) {
    int idx = j * 256 + tid;
    int kr = idx >> 6, nc = idx & 63;
    ts[kr][nc] = P[(size_t)(k0 + kr) * NN + n0 + nc];
  }
  __syncthreads();
#pragma unroll
  for (int j = 0; j < 16; ++j) {
    int idx = j * 256 + tid;
    int nr = idx >> 6, kc = idx & 63;
    Bt[(size_t)(n0 + nr) * KK + k0 + kc] = f2bf(ts[kc][nr]);
  }
}

// ---------------- GEMM, counted-vmcnt 3-deep pipeline ----------------
// A tile: [128 rows][32 f32] (128B rows, 8x 16B slots), phys slot = logical ^ (row&7).
// B tile: [128 rows][32 bf16] (64B rows, 4x 16B slots), phys = logical ^ ((row>>1)&3)
// (measured 0 bank conflicts in rounds 3/4). Both staged by global_load_lds (linear
// dest = wave-uniform base + lane*16B); swizzles realized by permuting the per-lane
// GLOBAL source slot (rule #21). Only vmem ops in the loop are the 6 gl_lds/iter,
// so s_waitcnt vmcnt(6) exactly means "loads issued 2 iters ago have retired".
__global__ __launch_bounds__(256) void gemm5(const float* __restrict__ X,
                                             const short* __restrict__ Bt,
                                             float* __restrict__ out) {
  __shared__ float Asf[3][BM * BK];   // 16 KB each (f32)
  __shared__ short Bsf[3][BN * BK];   // 8 KB each (bf16)

  const int tid = threadIdx.x;
  const int wid = tid >> 6, lane = tid & 63;
  const int lrow = lane & 15, kh = lane >> 4;
  const int wr = wid >> 1, wc = wid & 1;  // 2x2 wave grid; wave tile 64 x 64

  // XCD-bijective swizzle (512 blocks, 512%8==0)
  const int bid = blockIdx.x;
  const int tile = (bid & 7) * 64 + (bid >> 3);
  const int m0 = (tile >> 2) * BM;   // 128 row-blocks
  const int n0 = (tile & 3) * BN;    // 4 col-blocks (consecutive tiles share A rows)

  // ---- A staging descriptors: 4 gl_lds per wave, 1 KB each ----
  const float* aSrc[4];
  int aDst[4];
#pragma unroll
  for (int q = 0; q < 4; ++q) {
    int inst = wid * 4 + q;                     // 0..15
    int row = inst * 8 + (lane >> 3);           // 0..127
    int slot = (lane & 7) ^ ((lane >> 3) & 7);  // pre-swizzled source slot
    aSrc[q] = X + (size_t)(m0 + row) * KK + slot * 4;
    aDst[q] = inst * 256;                       // floats (linear dest)
  }
  // ---- B staging descriptors: 2 gl_lds per wave ----
  const int kd = (lane & 3) ^ ((lane >> 3) & 3);
  const short* bSrc[2];
  int bDst[2];
#pragma unroll
  for (int p = 0; p < 2; ++p) {
    int R0 = (p * 4 + wid) * 16;
    bDst[p] = R0 * 32;                          // shorts (linear dest)
    bSrc[p] = Bt + (size_t)(n0 + R0 + (lane >> 2)) * KK + kd * 8;
  }

  // ---- fragment LDS offsets (t-invariant; buffer base added per iter) ----
  int offA[4][2], offB[4];
#pragma unroll
  for (int m = 0; m < 4; ++m) {
    int r = wr * 64 + m * 16 + lrow;
    offA[m][0] = r * 32 + (((2 * kh) ^ (r & 7)) << 2);      // floats
    offA[m][1] = r * 32 + (((2 * kh + 1) ^ (r & 7)) << 2);  // floats
  }
#pragma unroll
  for (int n = 0; n < 4; ++n) {
    int r = wc * 64 + n * 16 + lrow;
    offB[n] = r * 32 + ((kh ^ ((r >> 1) & 3)) << 3);        // shorts
  }

  f32x4 acc[4][4];
#pragma unroll
  for (int m = 0; m < 4; ++m)
#pragma unroll
    for (int n = 0; n < 4; ++n) acc[m][n] = (f32x4)0.0f;

  auto compute = [&](int b) {
    const float* ab = &Asf[b][0];
    const short* bb = &Bsf[b][0];
    bf16x8 af[4], bfr[4];
#pragma unroll
    for (int m = 0; m < 4; ++m) {
      f32x4 lo = *(const f32x4*)(ab + offA[m][0]);
      f32x4 hi = *(const f32x4*)(ab + offA[m][1]);
      af[m] = cvt8(lo, hi);
    }
#pragma unroll
    for (int n = 0; n < 4; ++n) bfr[n] = *(const bf16x8*)(bb + offB[n]);
#pragma unroll
    for (int m = 0; m < 4; ++m)
#pragma unroll
      for (int n = 0; n < 4; ++n)
        acc[m][n] = __builtin_amdgcn_mfma_f32_16x16x32_bf16(af[m], bfr[n], acc[m][n], 0, 0, 0);
  };

  // ---- prologue: issue iters 0 and 1 (6 vmem ops each) ----
#pragma unroll
  for (int q = 0; q < 4; ++q) gl_lds16(aSrc[q], &Asf[0][aDst[q]]);
#pragma unroll
  for (int p = 0; p < 2; ++p) gl_lds16(bSrc[p], &Bsf[0][bDst[p]]);
#pragma unroll
  for (int q = 0; q < 4; ++q) gl_lds16(aSrc[q] + BK, &Asf[1][aDst[q]]);
#pragma unroll
  for (int p = 0; p < 2; ++p) gl_lds16(bSrc[p] + BK, &Bsf[1][bDst[p]]);

  // ---- main loop: one raw barrier per K-step, vmcnt(6) steady-state ----
  int b0 = 0;
  for (int t = 0; t < NT - 2; ++t) {
    asm volatile("s_waitcnt vmcnt(6)" ::: "memory");  // iter-t loads retired (in-order)
    __builtin_amdgcn_s_barrier();                     // all waves' iter-t loads landed;
                                                      // all waves done reading buf[(t-1)%3]
    int b2 = b0 + 2; if (b2 >= 3) b2 -= 3;
#pragma unroll
    for (int q = 0; q < 4; ++q) gl_lds16(aSrc[q] + (size_t)(t + 2) * BK, &Asf[b2][aDst[q]]);
#pragma unroll
    for (int p = 0; p < 2; ++p) gl_lds16(bSrc[p] + (size_t)(t + 2) * BK, &Bsf[b2][bDst[p]]);
    compute(b0);
    b0 = (b0 == 2) ? 0 : b0 + 1;
  }
  // t = NT-2: nothing new issued; vmcnt(6) still guarantees iter-(NT-2) retired
  asm volatile("s_waitcnt vmcnt(6)" ::: "memory");
  __builtin_amdgcn_s_barrier();
  compute(b0);
  b0 = (b0 == 2) ? 0 : b0 + 1;
  // t = NT-1: drain everything
  asm volatile("s_waitcnt vmcnt(0)" ::: "memory");
  __builtin_amdgcn_s_barrier();
  compute(b0);

  // ---- write Xp into p1 (C/D layout: col = lane&15, row = (lane>>4)*4 + reg) ----
#pragma unroll
  for (int m = 0; m < 4; ++m)
#pragma unroll
    for (int n = 0; n < 4; ++n)
#pragma unroll
      for (int r = 0; r < 4; ++r) {
        int row = m0 + wr * 64 + m * 16 + kh * 4 + r;
        int col = n0 + wc * 64 + n * 16 + lrow;
        out[(size_t)row * OUTW + 1 + col] = acc[m][n][r];
      }
}

// ---------------- epilogue: expand features from p1 ----------------
__global__ __launch_bounds__(512) void epi_k(float* __restrict__ out) {
  const int r = blockIdx.x;
  const int c = threadIdx.x;  // 0..511
  float* row = out + (size_t)r * OUTW;
  __shared__ float s[NN];
  float xp = row[1 + c];
  s[c] = xp;
  __syncthreads();
  float p2 = xp * xp;
  float p3 = p2 * xp;
  float sq = sqrtf(fabsf(xp) + 1e-8f);
  float pr = (c < 511) ? s[0] * s[c + 1] : s[1] * s[2];
  if (c == 0) row[0] = 1.0f;
  row[513 + c] = p2;
  row[1025 + c] = p3;
  row[1537 + c] = pr;
  row[2049 + c] = sq;
}

// ---------------- fallback (no workspace): round-1 path ----------------
#define FBM 128
#define FBN 128
#define FPAD 40

__global__ __launch_bounds__(256) void gemm_k(const float* __restrict__ A,
                                              const float* __restrict__ B,
                                              float* __restrict__ out) {
  __shared__ __align__(16) short Asf[FBM][FPAD];
  __shared__ __align__(16) short Bsf[FBN][FPAD];
  const int tid = threadIdx.x;
  const int bx = blockIdx.x;
  const int m0 = (bx >> 2) * FBM;
  const int n0 = (bx & 3) * FBN;
  const int wid = tid >> 6, lane = tid & 63;
  const int wr = wid >> 1, wc = wid & 1;
  const int lrow = lane & 15, kh = lane >> 4;
  f32x4 acc[4][4];
#pragma unroll
  for (int i = 0; i < 4; i++)
#pragma unroll
    for (int j = 0; j < 4; j++) acc[i][j] = (f32x4)0.0f;
  for (int k0 = 0; k0 < KK; k0 += BK) {
#pragma unroll
    for (int i = 0; i < 4; i++) {
      int fid = i * 256 + tid;
      int ar = fid >> 3, ac = (fid & 7) << 2;
      f32x4 v = *(const f32x4*)(A + (size_t)(m0 + ar) * KK + (k0 + ac));
      short h0 = f2bf(v[0]), h1 = f2bf(v[1]), h2 = f2bf(v[2]), h3 = f2bf(v[3]);
      Asf[ar][ac] = h0; Asf[ar][ac + 1] = h1; Asf[ar][ac + 2] = h2; Asf[ar][ac + 3] = h3;
    }
#pragma unroll
    for (int i = 0; i < 4; i++) {
      int fid = i * 256 + tid;
      int br = fid >> 5, bc = (fid & 31) << 2;
      f32x4 v = *(const f32x4*)(B + (size_t)(k0 + br) * NN + (n0 + bc));
#pragma unroll
      for (int j = 0; j < 4; j++) Bsf[bc + j][br] = f2bf(v[j]);
    }
    __syncthreads();
    bf16x8 af[4], bf[4];
#pragma unroll
    for (int m = 0; m < 4; m++) af[m] = *(const bf16x8*)&Asf[wr * 64 + m * 16 + lrow][kh * 8];
#pragma unroll
    for (int n = 0; n < 4; n++) bf[n] = *(const bf16x8*)&Bsf[wc * 64 + n * 16 + lrow][kh * 8];
#pragma unroll
    for (int m = 0; m < 4; m++)
#pragma unroll
      for (int n = 0; n < 4; n++)
        acc[m][n] = __builtin_amdgcn_mfma_f32_16x16x32_bf16(af[m], bf[n], acc[m][n], 0, 0, 0);
    __syncthreads();
  }
#pragma unroll
  for (int m = 0; m < 4; m++)
#pragma unroll
    for (int n = 0; n < 4; n++)
#pragma unroll
      for (int r = 0; r < 4; r++) {
        int row = m0 + wr * 64 + m * 16 + kh * 4 + r;
        int col = n0 + wc * 64 + n * 16 + lrow;
        out[(size_t)row * OUTW + 1 + col] = acc[m][n][r];
      }
}

extern "C" void kernel_launch(void* const* d_in, const int* in_sizes, int n_in,
                              void* d_out, int out_size, void* d_ws, size_t ws_size,
                              hipStream_t stream) {
  const float* X = (const float*)d_in[0];
  const float* P = (const float*)d_in[1];
  float* out = (float*)d_out;
  (void)in_sizes; (void)n_in; (void)out_size;

  if (ws_size >= (size_t)NN * KK * sizeof(short)) {
    short* Bt = (short*)d_ws;
    prep_b<<<dim3(256), dim3(256), 0, stream>>>(P, Bt);
    gemm5<<<dim3((MM / BM) * (NN / BN)), dim3(256), 0, stream>>>(X, Bt, out);
  } else {
    gemm_k<<<dim3(512), dim3(256), 0, stream>>>(X, P, out);
  }
  epi_k<<<dim3(MM), dim3(512), 0, stream>>>(out);
}

// Round 6
// 135.933 us; speedup vs baseline: 1.1352x; 1.1352x over previous
//
#include <hip/hip_runtime.h>
#include <hip/hip_bf16.h>
#include <math.h>

// Polynomial feature map: Xp = X @ P; out = [bias | Xp | Xp^2 | Xp^3 | pairs | sqrt(|Xp|+eps)]
// X: [16384, 2048] f32, P: [2048, 512] f32, out: [16384, 2561] f32.
// pairs (triu k=1, first 512): c<511 -> Xp[:,0]*Xp[:,c+1]; c==511 -> Xp[:,1]*Xp[:,2]
//
// Path: prep_b (P -> Bt bf16 in ws) ; gemm6 (128x128 tile, r4's verified bf16 LDS
// layouts + 3-buffer 2-iter-lead counted-vmcnt pipeline, raw s_barrier) writes p1 ;
// epi_k expands remaining regions reading p1 back (L2/L3-hot).

typedef __attribute__((ext_vector_type(4))) float f32x4;
typedef __attribute__((ext_vector_type(8))) short bf16x8;

#define MM 16384
#define NN 512
#define KK 2048
#define OUTW 2561

#define BM 128
#define BN 128
#define BK 32
#define NT (KK / BK)  // 64

__device__ __forceinline__ short f2bf(float x) {
  union { __hip_bfloat16 b; short s; } u;
  u.b = __float2bfloat16(x);  // hw RNE; compiler pairs into v_cvt_pk_bf16_f32
  return u.s;
}

__device__ __forceinline__ bf16x8 cvt8(f32x4 a, f32x4 b) {
  bf16x8 r;
  r[0] = f2bf(a[0]); r[1] = f2bf(a[1]); r[2] = f2bf(a[2]); r[3] = f2bf(a[3]);
  r[4] = f2bf(b[0]); r[5] = f2bf(b[1]); r[6] = f2bf(b[2]); r[7] = f2bf(b[3]);
  return r;
}

__device__ __forceinline__ void gl_lds16(const void* g, void* l) {
  __builtin_amdgcn_global_load_lds((const __attribute__((address_space(1))) unsigned int*)g,
                                   (__attribute__((address_space(3))) unsigned int*)l, 16, 0, 0);
}

// ---------------- prep: P [K][N] f32 -> Bt [N][K] bf16 ----------------
__global__ __launch_bounds__(256) void prep_b(const float* __restrict__ P, short* __restrict__ Bt) {
  __shared__ float ts[64][65];
  const int tid = threadIdx.x;
  const int k0 = (blockIdx.x >> 3) * 64;  // 32 k-blocks
  const int n0 = (blockIdx.x & 7) * 64;   // 8 n-blocks
#pragma unroll
  for (int j = 0; j < 16; ++j) {
    int idx = j * 256 + tid;
    int kr = idx >> 6, nc = idx & 63;
    ts[kr][nc] = P[(size_t)(k0 + kr) * NN + n0 + nc];
  }
  __syncthreads();
#pragma unroll
  for (int j = 0; j < 16; ++j) {
    int idx = j * 256 + tid;
    int nr = idx >> 6, kc = idx & 63;
    Bt[(size_t)(n0 + nr) * KK + k0 + kc] = f2bf(ts[kc][nr]);
  }
}

// ---------------- GEMM: r4 data path + counted-vmcnt 3-deep pipeline ----------------
// LDS tiles [row][32 bf16] (64B rows, 4x 16B slots), slot' = slot ^ ((row>>1)&3)
// -- measured 0 bank conflicts (rounds 3/4) on both ds_write_b128 staging and
// ds_read_b128 fragments. B staged by global_load_lds (linear dest); its swizzle is
// realized by permuting the per-lane GLOBAL source k-slot (rule #21).
//
// vmcnt ledger: per iter u the vm issue order is [A-loads(u+4) x4, B-glds(u+2) x2].
// At top of iter u outstanding = [A(u+2)x4, B(u)x2, A(u+3)x4, B(u+1)x2];
// s_waitcnt vmcnt(6) retires A(u+2) (regs for this iter's cvt) and B(u) (LDS for
// this iter's compute), leaving iter u-1's 6 in flight. Tail peeled: vmcnt 6/2/2/0.
__global__ __launch_bounds__(256) void gemm6(const float* __restrict__ X,
                                             const short* __restrict__ Bt,
                                             float* __restrict__ out) {
  __shared__ short As[3][BM * BK];   // 8 KB each
  __shared__ short Bs[3][BN * BK];   // 8 KB each

  const int tid = threadIdx.x;
  const int wid = tid >> 6, lane = tid & 63;
  const int lrow = lane & 15, kh = lane >> 4;
  const int wr = wid >> 1, wc = wid & 1;  // 2x2 wave grid; wave tile 64 x 64

  // XCD-bijective swizzle (512 blocks, 512%8==0)
  const int bid = blockIdx.x;
  const int tile = (bid & 7) * 64 + (bid >> 3);
  const int m0 = (tile >> 2) * BM;   // 128 row-blocks
  const int n0 = (tile & 3) * BN;    // 4 col-blocks (consecutive tiles share A rows)

  // A: thread covers rows arow and arow+64, 8 floats at k = akq*8
  const int arow = tid >> 2, akq = tid & 3;
  const float* aG0 = X + (size_t)(m0 + arow) * KK + akq * 8;
  const float* aG1 = aG0 + (size_t)64 * KK;
  const int aoff0 = arow * 32 + ((akq ^ ((arow >> 1) & 3)) << 3);            // shorts
  const int aoff1 = (64 + arow) * 32 + ((akq ^ (((64 + arow) >> 1) & 3)) << 3);

  // B: 2 gl_lds per wave; load p covers B-rows (p*4+wid)*16 .. +15
  const int kd = (lane & 3) ^ ((lane >> 3) & 3);  // pre-swizzled source k-slot
  const short* bSrc[2];
  int bDst[2];
#pragma unroll
  for (int p = 0; p < 2; ++p) {
    int R0 = (p * 4 + wid) * 16;
    bDst[p] = R0 * 32;                          // shorts (linear dest)
    bSrc[p] = Bt + (size_t)(n0 + R0 + (lane >> 2)) * KK + kd * 8;
  }

  f32x4 acc[4][4];
#pragma unroll
  for (int m = 0; m < 4; ++m)
#pragma unroll
    for (int n = 0; n < 4; ++n) acc[m][n] = (f32x4)0.0f;

  f32x4 s0[4], s1[4];  // two A register sets (even/odd tiles)

  auto loadA = [&](f32x4 (&s)[4], int t) {
    const float* p0 = aG0 + (size_t)t * BK;
    const float* p1 = aG1 + (size_t)t * BK;
    s[0] = *(const f32x4*)p0; s[1] = *(const f32x4*)(p0 + 4);
    s[2] = *(const f32x4*)p1; s[3] = *(const f32x4*)(p1 + 4);
  };
  auto writeA = [&](f32x4 (&s)[4], int b) {
    *(bf16x8*)&As[b][aoff0] = cvt8(s[0], s[1]);
    *(bf16x8*)&As[b][aoff1] = cvt8(s[2], s[3]);
  };
  auto stageB = [&](int t, int b) {
#pragma unroll
    for (int p = 0; p < 2; ++p) gl_lds16(bSrc[p] + (size_t)t * BK, &Bs[b][bDst[p]]);
  };
  auto compute = [&](int b) {
    const short* ab = &As[b][0];
    const short* bb = &Bs[b][0];
    const int sw = (lrow >> 1) & 3;
    bf16x8 af[4], bfr[4];
#pragma unroll
    for (int m = 0; m < 4; ++m) {
      int r = wr * 64 + m * 16 + lrow;
      af[m] = *(const bf16x8*)(ab + r * 32 + ((kh ^ sw) << 3));
    }
#pragma unroll
    for (int n = 0; n < 4; ++n) {
      int r = wc * 64 + n * 16 + lrow;
      bfr[n] = *(const bf16x8*)(bb + r * 32 + ((kh ^ sw) << 3));
    }
#pragma unroll
    for (int m = 0; m < 4; ++m)
#pragma unroll
      for (int n = 0; n < 4; ++n)
        acc[m][n] = __builtin_amdgcn_mfma_f32_16x16x32_bf16(af[m], bfr[n], acc[m][n], 0, 0, 0);
  };

  // ---- prologue: queue = [A0x4, B0x2, A1x4, B1x2], then rotate ----
  loadA(s0, 0);
  stageB(0, 0);
  loadA(s1, 1);
  stageB(1, 1);
  asm volatile("s_waitcnt vmcnt(8)" ::: "memory");   // A0 retired
  writeA(s0, 0);
  loadA(s0, 2);                                      // queue [B0,A1,B1,A2]
  asm volatile("s_waitcnt vmcnt(6)" ::: "memory");   // B0, A1 retired
  writeA(s1, 1);
  loadA(s1, 3);                                      // queue [B1,A2,A3]

  // ---- main loop: tiles 0..NT-5 (pairs), steady vmcnt(6) ----
  for (int t = 0; t < NT - 4; t += 2) {
    asm volatile("s_waitcnt vmcnt(6) lgkmcnt(0)" ::: "memory");
    __builtin_amdgcn_s_barrier();
    writeA(s0, (t + 2) % 3);
    loadA(s0, t + 4);
    stageB(t + 2, (t + 2) % 3);
    compute(t % 3);

    asm volatile("s_waitcnt vmcnt(6) lgkmcnt(0)" ::: "memory");
    __builtin_amdgcn_s_barrier();
    writeA(s1, (t + 3) % 3);
    loadA(s1, t + 5);
    stageB(t + 3, (t + 3) % 3);
    compute((t + 1) % 3);
  }

  // ---- peeled tail: tiles NT-4..NT-1 (s0 holds A(NT-2), s1 holds A(NT-1)) ----
  // tile NT-4: queue [A(NT-2),B(NT-4),A(NT-1),B(NT-3)] -> vmcnt(6) retires thru B(NT-4)
  asm volatile("s_waitcnt vmcnt(6) lgkmcnt(0)" ::: "memory");
  __builtin_amdgcn_s_barrier();
  writeA(s0, (NT - 2) % 3);
  stageB(NT - 2, (NT - 2) % 3);
  compute((NT - 4) % 3);
  // tile NT-3: queue [A(NT-1),B(NT-3),B(NT-2)] -> vmcnt(2) retires thru B(NT-3)
  asm volatile("s_waitcnt vmcnt(2) lgkmcnt(0)" ::: "memory");
  __builtin_amdgcn_s_barrier();
  writeA(s1, (NT - 1) % 3);
  stageB(NT - 1, (NT - 1) % 3);
  compute((NT - 3) % 3);
  // tile NT-2: queue [B(NT-2),B(NT-1)] -> vmcnt(2) retires B(NT-2)
  asm volatile("s_waitcnt vmcnt(2) lgkmcnt(0)" ::: "memory");
  __builtin_amdgcn_s_barrier();
  compute((NT - 2) % 3);
  // tile NT-1: drain
  asm volatile("s_waitcnt vmcnt(0) lgkmcnt(0)" ::: "memory");
  __builtin_amdgcn_s_barrier();
  compute((NT - 1) % 3);

  // ---- write Xp into p1 (C/D layout: col = lane&15, row = (lane>>4)*4 + reg) ----
#pragma unroll
  for (int m = 0; m < 4; ++m)
#pragma unroll
    for (int n = 0; n < 4; ++n)
#pragma unroll
      for (int r = 0; r < 4; ++r) {
        int row = m0 + wr * 64 + m * 16 + kh * 4 + r;
        int col = n0 + wc * 64 + n * 16 + lrow;
        out[(size_t)row * OUTW + 1 + col] = acc[m][n][r];
      }
}

// ---------------- epilogue: expand features from p1 ----------------
__global__ __launch_bounds__(512) void epi_k(float* __restrict__ out) {
  const int r = blockIdx.x;
  const int c = threadIdx.x;  // 0..511
  float* row = out + (size_t)r * OUTW;
  __shared__ float s[NN];
  float xp = row[1 + c];
  s[c] = xp;
  __syncthreads();
  float p2 = xp * xp;
  float p3 = p2 * xp;
  float sq = sqrtf(fabsf(xp) + 1e-8f);
  float pr = (c < 511) ? s[0] * s[c + 1] : s[1] * s[2];
  if (c == 0) row[0] = 1.0f;
  row[513 + c] = p2;
  row[1025 + c] = p3;
  row[1537 + c] = pr;
  row[2049 + c] = sq;
}

// ---------------- fallback (no workspace): round-1 path ----------------
#define FBM 128
#define FBN 128
#define FPAD 40

__global__ __launch_bounds__(256) void gemm_k(const float* __restrict__ A,
                                              const float* __restrict__ B,
                                              float* __restrict__ out) {
  __shared__ __align__(16) short Asf[FBM][FPAD];
  __shared__ __align__(16) short Bsf[FBN][FPAD];
  const int tid = threadIdx.x;
  const int bx = blockIdx.x;
  const int m0 = (bx >> 2) * FBM;
  const int n0 = (bx & 3) * FBN;
  const int wid = tid >> 6, lane = tid & 63;
  const int wr = wid >> 1, wc = wid & 1;
  const int lrow = lane & 15, kh = lane >> 4;
  f32x4 acc[4][4];
#pragma unroll
  for (int i = 0; i < 4; i++)
#pragma unroll
    for (int j = 0; j < 4; j++) acc[i][j] = (f32x4)0.0f;
  for (int k0 = 0; k0 < KK; k0 += BK) {
#pragma unroll
    for (int i = 0; i < 4; i++) {
      int fid = i * 256 + tid;
      int ar = fid >> 3, ac = (fid & 7) << 2;
      f32x4 v = *(const f32x4*)(A + (size_t)(m0 + ar) * KK + (k0 + ac));
      short h0 = f2bf(v[0]), h1 = f2bf(v[1]), h2 = f2bf(v[2]), h3 = f2bf(v[3]);
      Asf[ar][ac] = h0; Asf[ar][ac + 1] = h1; Asf[ar][ac + 2] = h2; Asf[ar][ac + 3] = h3;
    }
#pragma unroll
    for (int i = 0; i < 4; i++) {
      int fid = i * 256 + tid;
      int br = fid >> 5, bc = (fid & 31) << 2;
      f32x4 v = *(const f32x4*)(B + (size_t)(k0 + br) * NN + (n0 + bc));
#pragma unroll
      for (int j = 0; j < 4; j++) Bsf[bc + j][br] = f2bf(v[j]);
    }
    __syncthreads();
    bf16x8 af[4], bf[4];
#pragma unroll
    for (int m = 0; m < 4; m++) af[m] = *(const bf16x8*)&Asf[wr * 64 + m * 16 + lrow][kh * 8];
#pragma unroll
    for (int n = 0; n < 4; n++) bf[n] = *(const bf16x8*)&Bsf[wc * 64 + n * 16 + lrow][kh * 8];
#pragma unroll
    for (int m = 0; m < 4; m++)
#pragma unroll
      for (int n = 0; n < 4; n++)
        acc[m][n] = __builtin_amdgcn_mfma_f32_16x16x32_bf16(af[m], bf[n], acc[m][n], 0, 0, 0);
    __syncthreads();
  }
#pragma unroll
  for (int m = 0; m < 4; m++)
#pragma unroll
    for (int n = 0; n < 4; n++)
#pragma unroll
      for (int r = 0; r < 4; r++) {
        int row = m0 + wr * 64 + m * 16 + kh * 4 + r;
        int col = n0 + wc * 64 + n * 16 + lrow;
        out[(size_t)row * OUTW + 1 + col] = acc[m][n][r];
      }
}

extern "C" void kernel_launch(void* const* d_in, const int* in_sizes, int n_in,
                              void* d_out, int out_size, void* d_ws, size_t ws_size,
                              hipStream_t stream) {
  const float* X = (const float*)d_in[0];
  const float* P = (const float*)d_in[1];
  float* out = (float*)d_out;
  (void)in_sizes; (void)n_in; (void)out_size;

  if (ws_size >= (size_t)NN * KK * sizeof(short)) {
    short* Bt = (short*)d_ws;
    prep_b<<<dim3(256), dim3(256), 0, stream>>>(P, Bt);
    gemm6<<<dim3((MM / BM) * (NN / BN)), dim3(256), 0, stream>>>(X, Bt, out);
  } else {
    gemm_k<<<dim3(512), dim3(256), 0, stream>>>(X, P, out);
  }
  epi_k<<<dim3(MM), dim3(512), 0, stream>>>(out);
}